// Round 4
// baseline (123.112 us; speedup 1.0000x reference)
//
#include <hip/hip_runtime.h>
#include <math.h>

#define NBATCH 8192
#define NNEI 256
#define NROLE 3
#define NHID 32
#define NDIM 6

typedef float v2f __attribute__((ext_vector_type(2)));
typedef unsigned long long ull;

// Direct global->LDS staging, 16B/lane ONLY (the HW-verified width: m97).
// LDS dest is WAVE-UNIFORM base; HW adds lane*16 (m104). Global src is
// per-lane. R3's 12B variant produced NaN (lane-stride quirk suspected).
__device__ __forceinline__ void stage_lds16(const float* g, float* l) {
  __builtin_amdgcn_global_load_lds(
      (const __attribute__((address_space(1))) void*)g,
      (__attribute__((address_space(3))) void*)l, 16, 0, 0);
}

// MLP score via packed-f32 pairs (v_pk_fma_f32): Linear(6,32)->ReLU->Linear(32,1).
// Weight pointers MUST be wave-uniform (readfirstlane'd role) so weight reads
// stay s_load scalar traffic — R5 showed losing this costs 4x.
__device__ __forceinline__ float mlp_score(const float x0, const float x1,
                                           const float x2, const float x3,
                                           const float x4, const float x5,
                                           const float* __restrict__ w1,
                                           const float* __restrict__ bb,
                                           const float* __restrict__ w2,
                                           const float b2v) {
  const float x[NDIM] = {x0, x1, x2, x3, x4, x5};
  v2f ac0 = {0.f, 0.f}, ac1 = {0.f, 0.f}, ac2 = {0.f, 0.f}, ac3 = {0.f, 0.f};
#pragma unroll
  for (int h = 0; h < NHID; h += 8) {
    v2f a0 = *(const v2f*)(bb + h + 0);
    v2f a1 = *(const v2f*)(bb + h + 2);
    v2f a2 = *(const v2f*)(bb + h + 4);
    v2f a3 = *(const v2f*)(bb + h + 6);
#pragma unroll
    for (int d = 0; d < NDIM; ++d) {
      const float xv = x[d];
      const v2f xv2 = {xv, xv};
      const float* wc = w1 + d * NHID + h;  // uniform addr -> s_load
      a0 += xv2 * (*(const v2f*)(wc + 0));  // -ffp-contract -> v_pk_fma_f32
      a1 += xv2 * (*(const v2f*)(wc + 2));
      a2 += xv2 * (*(const v2f*)(wc + 4));
      a3 += xv2 * (*(const v2f*)(wc + 6));
    }
    a0.x = fmaxf(a0.x, 0.f); a0.y = fmaxf(a0.y, 0.f);
    a1.x = fmaxf(a1.x, 0.f); a1.y = fmaxf(a1.y, 0.f);
    a2.x = fmaxf(a2.x, 0.f); a2.y = fmaxf(a2.y, 0.f);
    a3.x = fmaxf(a3.x, 0.f); a3.y = fmaxf(a3.y, 0.f);
    ac0 += a0 * (*(const v2f*)(w2 + h + 0));
    ac1 += a1 * (*(const v2f*)(w2 + h + 2));
    ac2 += a2 * (*(const v2f*)(w2 + h + 4));
    ac3 += a3 * (*(const v2f*)(w2 + h + 6));
  }
  const v2f st = (ac0 + ac1) + (ac2 + ac3);
  return b2v + st.x + st.y;
}

// Ballot-count + perm scatter for one 64-neighbor chunk. c = global chunk id
// 0..7 (batch q = c>>2, cc = c&3). Writes only a 4B index per active lane;
// states/trust are staged raw by global_load_lds.
__device__ __forceinline__ void do_chunk(const int c, const int lane,
                                         const int rolev, const int maskv,
                                         int (*perm)[NNEI], int* scnt) {
  const int q = c >> 2, cc = c & 3;
  const bool active = (maskv != 0);
  const ull bal0 = __ballot(active && (rolev == 0));
  const ull bal1 = __ballot(active && (rolev == 1));
  const ull bal2 = __ballot(active && (rolev == 2));
  const int n0 = __popcll(bal0);
  const int n1 = __popcll(bal1);
  if (lane < 3) {
    const int n2 = __popcll(bal2);
    scnt[q * 12 + cc * 3 + lane] = (lane == 0) ? n0 : (lane == 1) ? n1 : n2;
  }
  if (active) {
    const ull mybal = (rolev == 0) ? bal0 : (rolev == 1) ? bal1 : bal2;
    const int rank = __popcll(mybal & ((1ull << lane) - 1ull));
    const int pre = ((rolev >= 1) ? n0 : 0) + ((rolev >= 2) ? n1 : 0);
    perm[q][cc * 64 + pre + rank] = cc * 64 + lane;  // chunk-segmented dense
  }
}

// 2 batches per 192-thread block (8-WG/CU cap x 2 = 16 batches/CU-generation).
// Phase 1: role/mask -> VGPR (issued first), states+trust -> LDS via
// 16B global_load_lds (zero VGPR, all in flight at once), ballot -> 4B perm
// scatter. ONE __syncthreads (drains vmcnt for the stages).
// Phase 3: wave r does role r for batch 0 then batch 1 (independent chains,
// shared L1-hot weights). Softmax max-subtraction cancels exactly in
// mf = sum(e*tw*v)/sum(e*tw), so no max chain (scores O(1..12), no overflow).
__global__ __launch_bounds__(192, 8) void hmf_main(
    const float* __restrict__ states,
    const int* __restrict__ roles,
    const int* __restrict__ maskp,   // bool arrives as int32
    const float* __restrict__ trust,
    const float* __restrict__ W1,    // [R][D][H]
    const float* __restrict__ b1,    // [R][H]
    const float* __restrict__ W2,    // [R][H]
    const float* __restrict__ b2g,   // [R]
    float* __restrict__ out) {
  const int tid = threadIdx.x;
  const int wave = tid >> 6;   // 0..2
  const int lane = tid & 63;
  const int b0 = blockIdx.x * 2;

  // stg[q][0..1535]  = raw states of batch b0+q (neighbor n at [n*6..n*6+6))
  // stg[q][1536..1791] = trust of batch b0+q
  __shared__ float stg[2][1792];   // 14 KB
  __shared__ int perm[2][NNEI];    // 2 KB, perm[densepos]=rawidx
  __shared__ int scnt[24];         // [q*12 + cc*3 + r]

  // ---- phase 1a: role/mask loads FIRST (their vmcnt wait then leaves the
  // later-issued stage ops in flight), then all 16B stages back-to-back ----
  const int cA = wave;              // chunks 0,1,2  (batch 0)
  const int cB = wave + 3;          // chunks 3,4,5  (3 -> b0; 4,5 -> b1)
  const int cC = wave + 6;          // chunks 6,7    (batch 1; wave<2 only)
  const bool hasC = (wave < 2);

  const size_t giA = (size_t)(b0 + (cA >> 2)) * NNEI + (size_t)((cA & 3) * 64 + lane);
  const size_t giB = (size_t)(b0 + (cB >> 2)) * NNEI + (size_t)((cB & 3) * 64 + lane);
  const int rlA = roles[giA];
  const int mkA = maskp[giA];
  const int rlB = roles[giB];
  const int mkB = maskp[giB];
  int rlC = 0, mkC = 0;
  if (hasC) {
    const size_t giC = (size_t)(b0 + (cC >> 2)) * NNEI + (size_t)((cC & 3) * 64 + lane);
    rlC = roles[giC];
    mkC = maskp[giC];
  }

  // 14 x 1024B segments (per batch: 6 states + 1 trust), round-robin over
  // waves. Segment s: q = s/7, ss = s%7; ss<6 -> states, ss==6 -> trust.
  // All bases 1024B-aligned; per-lane global addr = base + lane*16B.
#pragma unroll
  for (int k = 0; k < 5; ++k) {
    const int s = wave + k * 3;
    if (s < 14) {                    // wave-uniform branch
      const int q = s / 7, ss = s % 7;
      const float* g = (ss < 6)
          ? (states + (size_t)(b0 + q) * (NNEI * NDIM) + (size_t)(ss * 256 + lane * 4))
          : (trust + (size_t)(b0 + q) * NNEI + (size_t)(lane * 4));
      stage_lds16(g, &stg[q][ss * 256]);
    }
  }

  // ---- phase 1b: ballots + perm scatter (consumes only role/mask) ----
  do_chunk(cA, lane, rlA, mkA, perm, scnt);
  do_chunk(cB, lane, rlB, mkB, perm, scnt);
  if (hasC) do_chunk(cC, lane, rlC, mkC, perm, scnt);

  __syncthreads();  // drains vmcnt (stages landed) + lgkm + barrier

  // ---- phase 3: wave r handles role r for both batches ----
  const int r = __builtin_amdgcn_readfirstlane(wave);
  const float* w1 = W1 + r * (NDIM * NHID);
  const float* bb = b1 + r * NHID;
  const float* w2 = W2 + r * NHID;
  const float b2v = b2g[r];

#pragma unroll
  for (int q = 0; q < 2; ++q) {
    int cwv[4], prw[4];
#pragma unroll
    for (int w = 0; w < 4; ++w) {
      const int a0 = scnt[q * 12 + w * 3 + 0];
      const int a1 = scnt[q * 12 + w * 3 + 1];
      const int a2 = scnt[q * 12 + w * 3 + 2];
      const int cv = (r == 0) ? a0 : (r == 1) ? a1 : a2;
      const int pv = ((r >= 1) ? a0 : 0) + ((r >= 2) ? a1 : 0);
      cwv[w] = __builtin_amdgcn_readfirstlane(cv);
      prw[w] = __builtin_amdgcn_readfirstlane(pv);
    }
    const int acc0 = cwv[0];
    const int acc1 = acc0 + cwv[1];
    const int acc2 = acc1 + cwv[2];
    const int cnt = acc2 + cwv[3];

    float q0, q1, q2, q3, q4, q5, q6, q7;  // {Se, Set, Sd0..Sd5}

    if (cnt <= 64) {
      // ---- FAST PATH (P ~ 1 - 1e-4): single 64-lane pass ----
      const bool act = lane < cnt;
      const bool s1 = lane >= acc0;
      const bool s2 = lane >= acc1;
      const bool s3 = lane >= acc2;
      int sub = s1 ? acc0 : 0; sub = s2 ? acc1 : sub; sub = s3 ? acc2 : sub;
      int wb = s1 ? 64 : 0;    wb = s2 ? 128 : wb;    wb = s3 ? 192 : wb;
      int pr = s1 ? prw[1] : prw[0]; pr = s2 ? prw[2] : pr; pr = s3 ? prw[3] : pr;
      int pos = wb + pr + (lane - sub);
      pos = (pos > NNEI - 1) ? (NNEI - 1) : pos;  // inactive lanes may overrun
      pos = (pos < 0) ? 0 : pos;
      int idx = perm[q][pos];
      idx = (idx > NNEI - 1) ? (NNEI - 1) : idx;  // unwritten perm slots = garbage
      idx = (idx < 0) ? 0 : idx;
      const float* s = &stg[q][idx * 6];
      float2 va = *(const float2*)(s);
      float2 vb2 = *(const float2*)(s + 2);
      float2 vc = *(const float2*)(s + 4);
      float tw = stg[q][1536 + idx];
      if (!act) {  // select-gate: garbage slots may hold anything
        va = make_float2(0.f, 0.f);
        vb2 = make_float2(0.f, 0.f);
        vc = make_float2(0.f, 0.f);
        tw = 0.f;
      }
      const float sc = mlp_score(va.x, va.y, vb2.x, vb2.y, vc.x, vc.y, w1, bb, w2, b2v);
      const float e = act ? __expf(sc) : 0.f;
      const float et = e * tw;
      q0 = e; q1 = et;
      q2 = et * va.x; q3 = et * va.y; q4 = et * vb2.x;
      q5 = et * vb2.y; q6 = et * vc.x; q7 = et * vc.y;
    } else {
      // ---- SLOW PATH (cold, ~3 lists in 24576): dynamic chunk loop ----
      q0 = q1 = q2 = q3 = q4 = q5 = q6 = q7 = 0.f;
      const int nch = (cnt + 63) >> 6;
      for (int c = 0; c < nch; ++c) {
        const int jj = c * 64 + lane;
        const bool act = jj < cnt;
        const bool s1 = jj >= acc0;
        const bool s2 = jj >= acc1;
        const bool s3 = jj >= acc2;
        int sub = s1 ? acc0 : 0; sub = s2 ? acc1 : sub; sub = s3 ? acc2 : sub;
        int wb = s1 ? 64 : 0;    wb = s2 ? 128 : wb;    wb = s3 ? 192 : wb;
        int pr = s1 ? prw[1] : prw[0]; pr = s2 ? prw[2] : pr; pr = s3 ? prw[3] : pr;
        int pos = wb + pr + (jj - sub);
        pos = (pos > NNEI - 1) ? (NNEI - 1) : pos;
        pos = (pos < 0) ? 0 : pos;
        int idx = perm[q][pos];
        idx = (idx > NNEI - 1) ? (NNEI - 1) : idx;
        idx = (idx < 0) ? 0 : idx;
        const float* s = &stg[q][idx * 6];
        float2 va = *(const float2*)(s);
        float2 vb2 = *(const float2*)(s + 2);
        float2 vc = *(const float2*)(s + 4);
        float tw = stg[q][1536 + idx];
        if (!act) {
          va = make_float2(0.f, 0.f);
          vb2 = make_float2(0.f, 0.f);
          vc = make_float2(0.f, 0.f);
          tw = 0.f;
        }
        const float sc = mlp_score(va.x, va.y, vb2.x, vb2.y, vc.x, vc.y, w1, bb, w2, b2v);
        const float e = act ? __expf(sc) : 0.f;
        const float et = e * tw;
        q0 += e; q1 += et;
        q2 = fmaf(et, va.x, q2); q3 = fmaf(et, va.y, q3);
        q4 = fmaf(et, vb2.x, q4); q5 = fmaf(et, vb2.y, q5);
        q6 = fmaf(et, vc.x, q6); q7 = fmaf(et, vc.y, q7);
      }
    }

    // ---- reduction: 3 xor steps x8 (independent), select, 3 xor steps x1 ----
#pragma unroll
    for (int off = 1; off <= 4; off <<= 1) {
      q0 += __shfl_xor(q0, off); q1 += __shfl_xor(q1, off);
      q2 += __shfl_xor(q2, off); q3 += __shfl_xor(q3, off);
      q4 += __shfl_xor(q4, off); q5 += __shfl_xor(q5, off);
      q6 += __shfl_xor(q6, off); q7 += __shfl_xor(q7, off);
    }
    const int g = lane & 7;
    float myq = q0;
    myq = (g == 1) ? q1 : myq;
    myq = (g == 2) ? q2 : myq;
    myq = (g == 3) ? q3 : myq;
    myq = (g == 4) ? q4 : myq;
    myq = (g == 5) ? q5 : myq;
    myq = (g == 6) ? q6 : myq;
    myq = (g == 7) ? q7 : myq;
    myq += __shfl_xor(myq, 8);
    myq += __shfl_xor(myq, 16);
    myq += __shfl_xor(myq, 32);
    // lane i now holds the 64-lane total of quantity (i & 7)
    const float Se = __shfl(myq, 0);
    const float Set = __shfl(myq, 1);
    const float denom = Se + 1e-8f;
    const float ws = fmaxf(Set / denom, 1e-8f);
    if (lane >= 2 && lane < 8) {
      out[(size_t)(b0 + q) * (NROLE * NDIM) + r * NDIM + (lane - 2)] =
          (myq / denom) / ws;
    }
  }
}

extern "C" void kernel_launch(void* const* d_in, const int* in_sizes, int n_in,
                              void* d_out, int out_size, void* d_ws, size_t ws_size,
                              hipStream_t stream) {
  const float* states = (const float*)d_in[0];
  const int* roles = (const int*)d_in[1];
  const int* maskp = (const int*)d_in[2];
  const float* trust = (const float*)d_in[3];
  const float* W1 = (const float*)d_in[4];
  const float* b1 = (const float*)d_in[5];
  const float* W2 = (const float*)d_in[6];
  const float* b2 = (const float*)d_in[7];
  float* out = (float*)d_out;

  hmf_main<<<NBATCH / 2, 192, 0, stream>>>(states, roles, maskp, trust, W1, b1, W2, b2, out);
}